// Round 6
// baseline (485.018 us; speedup 1.0000x reference)
//
#include <hip/hip_runtime.h>
#include <math.h>

#define NB 32768
#define ND 768
#define NH 256
#define NG 8
#define GSZ 96

typedef __attribute__((ext_vector_type(8))) short short8_t;
typedef __attribute__((ext_vector_type(4))) float f32x4;

__device__ __forceinline__ float gelu_exact(float v) {
    return 0.5f * v * (1.0f + erff(v * 0.7071067811865475f));
}
__device__ __forceinline__ float sigmoidf_(float v) {
    return 1.0f / (1.0f + expf(-v));
}
__device__ __forceinline__ unsigned short f2bf(float f) {
    union { float f; unsigned u; } a; a.f = f;
    unsigned r = a.u + 0x7FFF + ((a.u >> 16) & 1);
    return (unsigned short)(r >> 16);
}

// ---------------------------------------------------------------------------
// cvt_x: x f32 [B,768] -> xh bf16 (RNE)
// ---------------------------------------------------------------------------
__global__ __launch_bounds__(256) void cvt_x(
    const float* __restrict__ x, unsigned short* __restrict__ xh)
{
    const int stride = gridDim.x * 256;
    for (int i = blockIdx.x * 256 + threadIdx.x; i < 3145728; i += stride) {
        float4 a = *(const float4*)(x + (size_t)i * 8);
        float4 b = *(const float4*)(x + (size_t)i * 8 + 4);
        short8_t h;
        h[0] = f2bf(a.x); h[1] = f2bf(a.y); h[2] = f2bf(a.z); h[3] = f2bf(a.w);
        h[4] = f2bf(b.x); h[5] = f2bf(b.y); h[6] = f2bf(b.z); h[7] = f2bf(b.w);
        *(short8_t*)(xh + (size_t)i * 8) = h;
    }
}

// ---------------------------------------------------------------------------
// cvt_w: dw1[768,256] -> dw1T[256 col][768 k] bf16; dw2[256,768] -> dw2T[768][256]
// ---------------------------------------------------------------------------
__global__ __launch_bounds__(256) void cvt_w(
    const float* __restrict__ dw1, const float* __restrict__ dw2,
    unsigned short* __restrict__ dw1T, unsigned short* __restrict__ dw2T)
{
    const int t = threadIdx.x, b = blockIdx.x;
    if (b == 0) {
        for (int k8 = 0; k8 < 96; ++k8) {
            short8_t h;
            #pragma unroll
            for (int j = 0; j < 8; ++j)
                h[j] = f2bf(dw1[(size_t)(k8 * 8 + j) * 256 + t]);
            *(short8_t*)(dw1T + (size_t)t * 768 + k8 * 8) = h;
        }
    } else {
        int col = (b - 1) * 256 + t;
        for (int k8 = 0; k8 < 32; ++k8) {
            short8_t h;
            #pragma unroll
            for (int j = 0; j < 8; ++j)
                h[j] = f2bf(dw2[(size_t)(k8 * 8 + j) * 768 + col]);
            *(short8_t*)(dw2T + (size_t)col * 256 + k8 * 8) = h;
        }
    }
}

// ---------------------------------------------------------------------------
// mfma_bf16: out = act(A[M,K]bf16 @ BT[N,K]bf16^T + bias)
// 512 thr = 8 waves (2x4), tile 128 rows x 256 cols, K-step 32.
// LDS rows padded to 40 shorts (80B = 5*16B): frag-read lanes spread over
// 8 banks, 2-way (free). Frag maps validated in round 5.
// ACT 0: gelu -> bf16 out; ACT 1: sigmoid -> f32 out.
// ---------------------------------------------------------------------------
template<int ACT>
__global__ __launch_bounds__(512) void mfma_bf16(
    const unsigned short* __restrict__ A, const unsigned short* __restrict__ BT,
    const float* __restrict__ bias, void* __restrict__ outp,
    int N, int K, int colBlocks)
{
    __shared__ unsigned short As[128][40];
    __shared__ unsigned short Bs[256][40];

    const int tid = threadIdx.x;
    const int l = tid & 63;
    const int w = tid >> 6;
    const int wm = w >> 2, wn = w & 3;
    const int lg = l >> 4, lr = l & 15;
    const int rb = blockIdx.x / colBlocks;
    const int cb = blockIdx.x - rb * colBlocks;
    const int rowsBase = rb * 128, colBase = cb * 256;

    f32x4 acc[4][4];
    #pragma unroll
    for (int mi = 0; mi < 4; ++mi)
        #pragma unroll
        for (int ni = 0; ni < 4; ++ni) acc[mi][ni] = (f32x4){0.f, 0.f, 0.f, 0.f};

    const int sArow = tid >> 2, sAch = tid & 3;
    const int sBcol = tid >> 1, sBch = (tid & 1) * 2;
    const unsigned short* aSrc = A + (size_t)(rowsBase + sArow) * K + sAch * 8;
    const unsigned short* bSrc = BT + (size_t)(colBase + sBcol) * K + sBch * 8;

    for (int kb = 0; kb < K; kb += 32) {
        short8_t va = *(const short8_t*)(aSrc + kb);
        short8_t vb0 = *(const short8_t*)(bSrc + kb);
        short8_t vb1 = *(const short8_t*)(bSrc + kb + 8);
        *(short8_t*)&As[sArow][sAch * 8] = va;
        *(short8_t*)&Bs[sBcol][sBch * 8] = vb0;
        *(short8_t*)&Bs[sBcol][sBch * 8 + 8] = vb1;
        __syncthreads();

        short8_t af[4], bf[4];
        #pragma unroll
        for (int mi = 0; mi < 4; ++mi)
            af[mi] = *(const short8_t*)&As[wm * 64 + mi * 16 + lr][lg * 8];
        #pragma unroll
        for (int ni = 0; ni < 4; ++ni)
            bf[ni] = *(const short8_t*)&Bs[wn * 64 + ni * 16 + lr][lg * 8];
        #pragma unroll
        for (int mi = 0; mi < 4; ++mi)
            #pragma unroll
            for (int ni = 0; ni < 4; ++ni)
                acc[mi][ni] = __builtin_amdgcn_mfma_f32_16x16x32_bf16(
                    af[mi], bf[ni], acc[mi][ni], 0, 0, 0);
        __syncthreads();
    }

    // D: col = l&15, row = (l>>4)*4 + j  (round-5 verified)
    #pragma unroll
    for (int ni = 0; ni < 4; ++ni) {
        int col = colBase + wn * 64 + ni * 16 + lr;
        float bv = bias[col];
        #pragma unroll
        for (int mi = 0; mi < 4; ++mi) {
            int rbase = rowsBase + wm * 64 + mi * 16 + lg * 4;
            #pragma unroll
            for (int j = 0; j < 4; ++j) {
                float v = acc[mi][ni][j] + bv;
                if (ACT == 0) {
                    ((unsigned short*)outp)[(size_t)(rbase + j) * N + col] =
                        f2bf(gelu_exact(v));
                } else {
                    ((float*)outp)[(size_t)(rbase + j) * N + col] = sigmoidf_(v);
                }
            }
        }
    }
}

// ---------------------------------------------------------------------------
// k1r_p: partial u1 = x[:, kh] @ w1[kh, :] (fp32, K-split 2). Bit-identical
// math to round 5; lane->col remap {cl*8} -> {cl*4, 128+cl*4} makes both
// ws b128 reads conflict-free (consecutive chunks / broadcast).
// ---------------------------------------------------------------------------
__global__ __launch_bounds__(256) void k1r_p(
    const float* __restrict__ x, const float* __restrict__ w1,
    float* __restrict__ u1p)
{
    __shared__ float xs[32][132];
    __shared__ float ws[32][256];

    const int tid = threadIdx.x;
    const int l = tid & 63;
    const int wv = tid >> 6;
    const int h = l >> 5;
    const int cl = l & 31;
    const int r0w = wv * 32 + h * 16;
    const int rb = blockIdx.x >> 1;
    const int half = blockIdx.x & 1;
    const int rowsBase = rb * 128;
    const int kBase = half * 384;

    float acc[16][8];
    #pragma unroll
    for (int i = 0; i < 16; ++i)
        #pragma unroll
        for (int j = 0; j < 8; ++j) acc[i][j] = 0.0f;

    for (int kc = 0; kc < 12; ++kc) {
        const int kb = kBase + kc * 32;
        #pragma unroll
        for (int m = 0; m < 4; ++m) {
            int flat = m * 256 + tid;
            int r = flat >> 3, i4 = flat & 7;
            float4 v = *(const float4*)(x + (size_t)(rowsBase + r) * ND + kb + i4 * 4);
            xs[i4*4+0][r] = v.x; xs[i4*4+1][r] = v.y;
            xs[i4*4+2][r] = v.z; xs[i4*4+3][r] = v.w;
        }
        #pragma unroll
        for (int m = 0; m < 8; ++m) {
            int flat = m * 256 + tid;
            int k = flat >> 6, c = (flat & 63) * 4;
            *(float4*)&ws[k][c] = *(const float4*)(w1 + (size_t)(kb + k) * 256 + c);
        }
        __syncthreads();
        #pragma unroll 4
        for (int k = 0; k < 32; ++k) {
            float xv[16], wv8[8];
            *(float4*)&xv[0]  = *(const float4*)&xs[k][r0w];
            *(float4*)&xv[4]  = *(const float4*)&xs[k][r0w + 4];
            *(float4*)&xv[8]  = *(const float4*)&xs[k][r0w + 8];
            *(float4*)&xv[12] = *(const float4*)&xs[k][r0w + 12];
            *(float4*)&wv8[0] = *(const float4*)&ws[k][cl * 4];         // chunks 0-31
            *(float4*)&wv8[4] = *(const float4*)&ws[k][128 + cl * 4];   // chunks 32-63
            #pragma unroll
            for (int i = 0; i < 16; ++i)
                #pragma unroll
                for (int j = 0; j < 8; ++j)
                    acc[i][j] = fmaf(xv[i], wv8[j], acc[i][j]);
        }
        __syncthreads();
    }
    float* dst = u1p + (size_t)half * 8388608;
    #pragma unroll
    for (int i = 0; i < 16; ++i) {
        int row = rowsBase + r0w + i;
        *(float4*)(dst + (size_t)row * 256 + cl * 4)       = *(float4*)&acc[i][0];
        *(float4*)(dst + (size_t)row * 256 + 128 + cl * 4) = *(float4*)&acc[i][4];
    }
}

// ---------------------------------------------------------------------------
// k1_epi: h1 = gelu(LN(u1p0 + u1p1 + b1)); one wave per row
// ---------------------------------------------------------------------------
__global__ __launch_bounds__(256) void k1_epi(
    const float* __restrict__ u1p, const float* __restrict__ b1,
    const float* __restrict__ lng, const float* __restrict__ lnb,
    float* __restrict__ h1)
{
    const int wv = threadIdx.x >> 6, l = threadIdx.x & 63;
    const int row = blockIdx.x * 4 + wv;
    float4 a = *(const float4*)(u1p + (size_t)row * 256 + l * 4);
    float4 b = *(const float4*)(u1p + 8388608 + (size_t)row * 256 + l * 4);
    float4 bb = *(const float4*)(b1 + l * 4);
    float u[4] = {a.x + b.x + bb.x, a.y + b.y + bb.y,
                  a.z + b.z + bb.z, a.w + b.w + bb.w};
    float s = u[0] + u[1] + u[2] + u[3];
    float q = u[0]*u[0] + u[1]*u[1] + u[2]*u[2] + u[3]*u[3];
    #pragma unroll
    for (int o = 1; o < 64; o <<= 1) {
        s += __shfl_xor(s, o);
        q += __shfl_xor(q, o);
    }
    float mean = s * (1.0f / 256.0f);
    float var  = q * (1.0f / 256.0f) - mean * mean;
    float rstd = rsqrtf(var + 1e-5f);
    float4 g = *(const float4*)(lng + l * 4);
    float4 be = *(const float4*)(lnb + l * 4);
    float4 o;
    o.x = gelu_exact((u[0] - mean) * rstd * g.x + be.x);
    o.y = gelu_exact((u[1] - mean) * rstd * g.y + be.y);
    o.z = gelu_exact((u[2] - mean) * rstd * g.z + be.z);
    o.w = gelu_exact((u[3] - mean) * rstd * g.w + be.w);
    *(float4*)(h1 + (size_t)row * 256 + l * 4) = o;
}

// ---------------------------------------------------------------------------
// k2a_p: partial u2 = h1[:, kh] @ w2[kh, :]  (fp32, K-split 2)
// ---------------------------------------------------------------------------
__global__ __launch_bounds__(256) void k2a_p(
    const float* __restrict__ h1, const float* __restrict__ w2,
    float* __restrict__ u2p)
{
    __shared__ float xs[32][132];
    __shared__ float ws[32][128];

    const int tid = threadIdx.x;
    const int tc = tid & 15, tr = tid >> 4;
    const int c0 = tc * 4, c1 = 64 + tc * 4, r0 = tr * 8;
    const int rb = blockIdx.x >> 1, half = blockIdx.x & 1;
    const int rowsBase = rb * 128, kBase = half * 128;

    float acc[8][8];
    #pragma unroll
    for (int i = 0; i < 8; ++i)
        #pragma unroll
        for (int j = 0; j < 8; ++j) acc[i][j] = 0.0f;

    for (int kc = 0; kc < 4; ++kc) {
        const int kb = kBase + kc * 32;
        #pragma unroll
        for (int m = 0; m < 4; ++m) {
            int flat = m * 256 + tid;
            int r = flat >> 3, i4 = flat & 7;
            float4 v = *(const float4*)(h1 + (size_t)(rowsBase + r) * 256 + kb + i4 * 4);
            xs[i4*4+0][r] = v.x; xs[i4*4+1][r] = v.y;
            xs[i4*4+2][r] = v.z; xs[i4*4+3][r] = v.w;
        }
        #pragma unroll
        for (int m = 0; m < 4; ++m) {
            int flat = m * 256 + tid;
            int k = flat >> 5, c = (flat & 31) * 4;
            *(float4*)&ws[k][c] = *(const float4*)(w2 + (size_t)(kb + k) * 128 + c);
        }
        __syncthreads();
        #pragma unroll 8
        for (int k = 0; k < 32; ++k) {
            float xv[8], wv8[8];
            *(float4*)&xv[0]  = *(const float4*)&xs[k][r0];
            *(float4*)&xv[4]  = *(const float4*)&xs[k][r0 + 4];
            *(float4*)&wv8[0] = *(const float4*)&ws[k][c0];
            *(float4*)&wv8[4] = *(const float4*)&ws[k][c1];
            #pragma unroll
            for (int i = 0; i < 8; ++i)
                #pragma unroll
                for (int j = 0; j < 8; ++j)
                    acc[i][j] = fmaf(xv[i], wv8[j], acc[i][j]);
        }
        __syncthreads();
    }
    float* dst = u2p + (size_t)half * 4194304;
    #pragma unroll
    for (int i = 0; i < 8; ++i) {
        int row = rowsBase + r0 + i;
        *(float4*)(dst + (size_t)row * 128 + c0) = *(float4*)&acc[i][0];
        *(float4*)(dst + (size_t)row * 128 + c1) = *(float4*)&acc[i][4];
    }
}

// ---------------------------------------------------------------------------
// k3: h2 = gelu(u2p0+u2p1+b2) in-reg; logits = h2@w3 + b3 + gi; probs;
// constrained selection -> sel; scalar partials.
// ---------------------------------------------------------------------------
__global__ __launch_bounds__(128) void k3_router(
    const float* __restrict__ u2p, const float* __restrict__ w3,
    const float* __restrict__ b3, const float* __restrict__ gi,
    const float* __restrict__ b2, float* __restrict__ probsOut,
    float* __restrict__ selOut, float* __restrict__ scal)
{
    __shared__ float ws3[128][8];
    __shared__ float sAct[2], sP[2], sCnt[2][8];

    const int tid = threadIdx.x;
    *(float4*)&ws3[tid][0] = *(const float4*)(w3 + tid * 8);
    *(float4*)&ws3[tid][4] = *(const float4*)(w3 + tid * 8 + 4);
    __syncthreads();

    const int row = blockIdx.x * 128 + tid;
    const float* r0p = u2p + (size_t)row * 128;
    const float* r1p = u2p + 4194304 + (size_t)row * 128;

    float accg[8];
    #pragma unroll
    for (int g = 0; g < 8; ++g) accg[g] = 0.0f;
    #pragma unroll 4
    for (int k4 = 0; k4 < 32; ++k4) {
        float4 a = *(const float4*)(r0p + k4 * 4);
        float4 b = *(const float4*)(r1p + k4 * 4);
        float4 bb = *(const float4*)(b2 + k4 * 4);
        float hv4[4];
        hv4[0] = gelu_exact(a.x + b.x + bb.x);
        hv4[1] = gelu_exact(a.y + b.y + bb.y);
        hv4[2] = gelu_exact(a.z + b.z + bb.z);
        hv4[3] = gelu_exact(a.w + b.w + bb.w);
        #pragma unroll
        for (int t = 0; t < 4; ++t)
            #pragma unroll
            for (int g = 0; g < 8; ++g)
                accg[g] = fmaf(hv4[t], ws3[k4 * 4 + t][g], accg[g]);
    }

    float p[8], gs[8], cnt[8];
    float actCnt = 0.0f, pSum = 0.0f;
    #pragma unroll
    for (int g = 0; g < 8; ++g) {
        float lg = accg[g] + b3[g] + gi[g];
        p[g] = sigmoidf_(lg);
    }
    #pragma unroll
    for (int g = 0; g < 8; ++g) {
        int rank = 0;
        #pragma unroll
        for (int j = 0; j < 8; ++j) {
            rank += (p[j] > p[g]) ? 1 : 0;
            rank += (j < g && p[j] == p[g]) ? 1 : 0;
        }
        float act = (rank < 2) ? 1.0f
                  : ((rank < 6) ? ((p[g] > 0.5f) ? 1.0f : 0.0f) : 0.0f);
        gs[g] = (act - p[g]) + p[g];
        float over = (p[g] > 0.5f) ? 1.0f : 0.0f;
        cnt[g] = over;
        actCnt += over;
        pSum += p[g];
    }

    *(float4*)(probsOut + (size_t)row * 8)     = *(float4*)&p[0];
    *(float4*)(probsOut + (size_t)row * 8 + 4) = *(float4*)&p[4];
    *(float4*)(selOut   + (size_t)row * 8)     = *(float4*)&gs[0];
    *(float4*)(selOut   + (size_t)row * 8 + 4) = *(float4*)&gs[4];

    #pragma unroll
    for (int o = 32; o > 0; o >>= 1) {
        actCnt += __shfl_down(actCnt, o);
        pSum   += __shfl_down(pSum, o);
        #pragma unroll
        for (int g = 0; g < 8; ++g) cnt[g] += __shfl_down(cnt[g], o);
    }
    if ((tid & 63) == 0) {
        int w = tid >> 6;
        sAct[w] = actCnt; sP[w] = pSum;
        #pragma unroll
        for (int g = 0; g < 8; ++g) sCnt[w][g] = cnt[g];
    }
    __syncthreads();
    if (tid == 0) {
        const float invB = 1.0f / 32768.0f;
        atomicAdd(&scal[0], (sAct[0] + sAct[1]) * invB);
        atomicAdd(&scal[9], (sP[0] + sP[1]) * invB);
        #pragma unroll
        for (int g = 0; g < 8; ++g)
            atomicAdd(&scal[1 + g], (sCnt[0][g] + sCnt[1][g]) * invB);
    }
}

// ---------------------------------------------------------------------------
// k4: gmask = repeat(sel); mask = gmask * dwts; active_dims reduce
// ---------------------------------------------------------------------------
__global__ __launch_bounds__(256) void k4_mask(
    const float* __restrict__ sel, const float* __restrict__ dwts,
    float* __restrict__ gmaskOut, float* __restrict__ maskOut,
    float* __restrict__ activeDims)
{
    const int stride = gridDim.x * 256;
    float cntF = 0.0f;
    for (int i4 = blockIdx.x * 256 + threadIdx.x; i4 < 6291456; i4 += stride) {
        int row = i4 / 192;
        int rem = i4 - row * 192;
        int g = rem / 24;
        float v = sel[(size_t)row * 8 + g];
        float4 d = *(const float4*)(dwts + (size_t)i4 * 4);
        float4 gm = {v, v, v, v};
        float4 m = {v * d.x, v * d.y, v * d.z, v * d.w};
        *(float4*)(gmaskOut + (size_t)i4 * 4) = gm;
        *(float4*)(maskOut  + (size_t)i4 * 4) = m;
        cntF += (m.x > 0.5f ? 1.0f : 0.0f) + (m.y > 0.5f ? 1.0f : 0.0f)
              + (m.z > 0.5f ? 1.0f : 0.0f) + (m.w > 0.5f ? 1.0f : 0.0f);
    }
    #pragma unroll
    for (int o = 32; o > 0; o >>= 1) cntF += __shfl_down(cntF, o);
    __shared__ float sc[4];
    if ((threadIdx.x & 63) == 0) sc[threadIdx.x >> 6] = cntF;
    __syncthreads();
    if (threadIdx.x == 0)
        atomicAdd(activeDims, (sc[0] + sc[1] + sc[2] + sc[3]) * (1.0f / 32768.0f));
}

__global__ void kz_zero(float* s) { if (threadIdx.x < 11) s[threadIdx.x] = 0.0f; }

// ---------------------------------------------------------------------------
extern "C" void kernel_launch(void* const* d_in, const int* in_sizes, int n_in,
                              void* d_out, int out_size, void* d_ws, size_t ws_size,
                              hipStream_t stream)
{
    const float* x   = (const float*)d_in[0];
    const float* w1  = (const float*)d_in[1];
    const float* b1  = (const float*)d_in[2];
    const float* lng = (const float*)d_in[3];
    const float* lnb = (const float*)d_in[4];
    const float* w2  = (const float*)d_in[5];
    const float* b2  = (const float*)d_in[6];
    const float* w3  = (const float*)d_in[7];
    const float* b3  = (const float*)d_in[8];
    const float* dw1 = (const float*)d_in[9];
    const float* db1 = (const float*)d_in[10];
    const float* dw2 = (const float*)d_in[11];
    const float* db2 = (const float*)d_in[12];
    const float* gi  = (const float*)d_in[13];

    float* out   = (float*)d_out;
    float* mask  = out;                 // [B,768] output slot
    float* gmask = out + 25165824;      // [B,768] output slot
    float* dwts  = out + 50331648;      // [B,768] output slot
    float* probs = out + 75497472;      // [B,8]
    float* sel   = out + 75759616;      // [B,8]
    float* scal  = out + 76021760;      // 11 scalars

    // scratch in dead output slots:
    // mask slot: u1p [2][B][256] + h1 [B][256]  (dead until k4)
    float* u1p = mask;
    float* h1  = mask + 16777216;
    // gmask slot: u2p [2][B][128] + g1h bf16 + weight bf16 (dead until k4)
    float* u2p = gmask;
    unsigned short* g1h  = (unsigned short*)(gmask + 8388608);   // [B][256] bf16
    unsigned short* dw1T = (unsigned short*)(gmask + 12582912);  // [256][768] bf16
    unsigned short* dw2T = (unsigned short*)(gmask + 12681216);  // [768][256] bf16
    // dwts slot: xh bf16 [B][768] (dead once mfma0 done; mfma1 overwrites)
    unsigned short* xh = (unsigned short*)dwts;

    kz_zero<<<dim3(1), dim3(64), 0, stream>>>(scal);
    cvt_x<<<dim3(2048), dim3(256), 0, stream>>>(x, xh);
    cvt_w<<<dim3(4), dim3(256), 0, stream>>>(dw1, dw2, dw1T, dw2T);
    // router path (fp32, bit-identical to round 5)
    k1r_p<<<dim3(512), dim3(256), 0, stream>>>(x, w1, u1p);
    k1_epi<<<dim3(8192), dim3(256), 0, stream>>>(u1p, b1, lng, lnb, h1);
    k2a_p<<<dim3(512), dim3(256), 0, stream>>>(h1, w2, u2p);
    k3_router<<<dim3(256), dim3(128), 0, stream>>>(
        u2p, w3, b3, gi, b2, probs, sel, scal);
    // dim-importance path (pure bf16 MFMA; boundary 15 sigma away)
    mfma_bf16<0><<<dim3(256), dim3(512), 0, stream>>>(
        xh, dw1T, db1, (void*)g1h, 256, 768, 1);
    mfma_bf16<1><<<dim3(768), dim3(512), 0, stream>>>(
        g1h, dw2T, db2, (void*)dwts, 768, 256, 3);
    k4_mask<<<dim3(2048), dim3(256), 0, stream>>>(sel, dwts, gmask, mask, &scal[10]);
}

// Round 7
// 308.042 us; speedup vs baseline: 1.5745x; 1.5745x over previous
//
#include <hip/hip_runtime.h>
#include <math.h>

#define NB 32768
#define ND 768
#define NH 256
#define NG 8
#define GSZ 96

typedef __attribute__((ext_vector_type(8))) short short8_t;
typedef __attribute__((ext_vector_type(4))) float f32x4;

__device__ __forceinline__ float gelu_exact(float v) {
    return 0.5f * v * (1.0f + erff(v * 0.7071067811865475f));
}
__device__ __forceinline__ float sigmoidf_(float v) {
    return 1.0f / (1.0f + expf(-v));
}
__device__ __forceinline__ unsigned short f2bf(float f) {
    union { float f; unsigned u; } a; a.f = f;
    unsigned r = a.u + 0x7FFF + ((a.u >> 16) & 1);
    return (unsigned short)(r >> 16);
}
__device__ __forceinline__ void f2bf2(float f, unsigned short& hi, unsigned short& lo) {
    union { float f; unsigned u; } a; a.f = f;
    unsigned r = a.u + 0x7FFF + ((a.u >> 16) & 1);
    hi = (unsigned short)(r >> 16);
    union { unsigned u; float f; } hf; hf.u = (r >> 16) << 16;
    float rem = f - hf.f;
    union { float f; unsigned u; } b; b.f = rem;
    unsigned r2 = b.u + 0x7FFF + ((b.u >> 16) & 1);
    lo = (unsigned short)(r2 >> 16);
}

// ---------------------------------------------------------------------------
// cvt_wall: all weight conversions, parallel + coalesced reads.
// blocks 0..95:    w1[768,256]  -> w1Th/w1Tl [256][768] (split pair)
// blocks 96..191:  dw1[768,256] -> dw1T [256][768] (hi)
// blocks 192..287: dw2[256,768] -> dw2T [768][256] (hi)
// ---------------------------------------------------------------------------
__global__ __launch_bounds__(256) void cvt_wall(
    const float* __restrict__ w1, const float* __restrict__ dw1,
    const float* __restrict__ dw2, unsigned short* __restrict__ w1Th,
    unsigned short* __restrict__ w1Tl, unsigned short* __restrict__ dw1T,
    unsigned short* __restrict__ dw2T)
{
    const int b = blockIdx.x, t = threadIdx.x;
    if (b < 96) {
        int idx = b * 256 + t;
        int k8 = idx >> 8, c = idx & 255;
        short8_t h, lo;
        #pragma unroll
        for (int j = 0; j < 8; ++j) {
            unsigned short hi_, lo_;
            f2bf2(w1[(size_t)(k8 * 8 + j) * 256 + c], hi_, lo_);
            h[j] = (short)hi_; lo[j] = (short)lo_;
        }
        *(short8_t*)(w1Th + (size_t)c * 768 + k8 * 8) = h;
        *(short8_t*)(w1Tl + (size_t)c * 768 + k8 * 8) = lo;
    } else if (b < 192) {
        int idx = (b - 96) * 256 + t;
        int k8 = idx >> 8, c = idx & 255;
        short8_t h;
        #pragma unroll
        for (int j = 0; j < 8; ++j)
            h[j] = (short)f2bf(dw1[(size_t)(k8 * 8 + j) * 256 + c]);
        *(short8_t*)(dw1T + (size_t)c * 768 + k8 * 8) = h;
    } else {
        int idx = (b - 192) * 256 + t;
        int k8 = idx / 768, c = idx - k8 * 768;
        short8_t h;
        #pragma unroll
        for (int j = 0; j < 8; ++j)
            h[j] = (short)f2bf(dw2[(size_t)(k8 * 8 + j) * 768 + c]);
        *(short8_t*)(dw2T + (size_t)c * 256 + k8 * 8) = h;
    }
}

// ---------------------------------------------------------------------------
// mfma_u1: u1 = x @ w1  (split-3 bf16 MFMA, ~1e-5 rel err), f32 out, no bias.
// 256 thr = 4 waves (2x2), tile 128x128, K-step 32, grid 512 (2 col-blocks).
// A converted f32->hi/lo during staging; B pre-split (w1Th/w1Tl).
// Frag maps validated rounds 5-6.
// ---------------------------------------------------------------------------
__global__ __launch_bounds__(256) void mfma_u1(
    const float* __restrict__ x, const unsigned short* __restrict__ BTh,
    const unsigned short* __restrict__ BTl, float* __restrict__ u1)
{
    __shared__ unsigned short Ah[128][40];
    __shared__ unsigned short Al[128][40];
    __shared__ unsigned short Bh[128][40];
    __shared__ unsigned short Bl[128][40];

    const int tid = threadIdx.x;
    const int l = tid & 63;
    const int w = tid >> 6;
    const int wm = w >> 1, wn = w & 1;
    const int lg = l >> 4, lr = l & 15;
    const int rb = blockIdx.x >> 1;
    const int cb = blockIdx.x & 1;
    const int rowsBase = rb * 128, colBase = cb * 128;

    f32x4 acc[4][4];
    #pragma unroll
    for (int mi = 0; mi < 4; ++mi)
        #pragma unroll
        for (int ni = 0; ni < 4; ++ni) acc[mi][ni] = (f32x4){0.f, 0.f, 0.f, 0.f};

    for (int kb = 0; kb < ND; kb += 32) {
        // stage A: x 128 rows x 32 k f32 -> hi/lo bf16
        #pragma unroll
        for (int m = 0; m < 2; ++m) {
            int flat = m * 256 + tid;
            int row = flat >> 2, seg = flat & 3;
            const float* src = x + (size_t)(rowsBase + row) * ND + kb + seg * 8;
            float4 v0 = *(const float4*)src;
            float4 v1 = *(const float4*)(src + 4);
            float f[8] = {v0.x, v0.y, v0.z, v0.w, v1.x, v1.y, v1.z, v1.w};
            short8_t ph, pl;
            #pragma unroll
            for (int j = 0; j < 8; ++j) {
                unsigned short hi_, lo_;
                f2bf2(f[j], hi_, lo_);
                ph[j] = (short)hi_; pl[j] = (short)lo_;
            }
            *(short8_t*)&Ah[row][seg * 8] = ph;
            *(short8_t*)&Al[row][seg * 8] = pl;
        }
        // stage B: pre-split bf16, b128 loads
        #pragma unroll
        for (int m = 0; m < 2; ++m) {
            int flat = m * 256 + tid;
            int col = flat >> 2, seg = flat & 3;
            size_t off = (size_t)(colBase + col) * ND + kb + seg * 8;
            *(short8_t*)&Bh[col][seg * 8] = *(const short8_t*)(BTh + off);
            *(short8_t*)&Bl[col][seg * 8] = *(const short8_t*)(BTl + off);
        }
        __syncthreads();

        short8_t afh[4], afl[4], bfh[4], bfl[4];
        #pragma unroll
        for (int mi = 0; mi < 4; ++mi) {
            afh[mi] = *(const short8_t*)&Ah[wm * 64 + mi * 16 + lr][lg * 8];
            afl[mi] = *(const short8_t*)&Al[wm * 64 + mi * 16 + lr][lg * 8];
        }
        #pragma unroll
        for (int ni = 0; ni < 4; ++ni) {
            bfh[ni] = *(const short8_t*)&Bh[wn * 64 + ni * 16 + lr][lg * 8];
            bfl[ni] = *(const short8_t*)&Bl[wn * 64 + ni * 16 + lr][lg * 8];
        }
        #pragma unroll
        for (int mi = 0; mi < 4; ++mi)
            #pragma unroll
            for (int ni = 0; ni < 4; ++ni) {
                acc[mi][ni] = __builtin_amdgcn_mfma_f32_16x16x32_bf16(
                    afl[mi], bfh[ni], acc[mi][ni], 0, 0, 0);
                acc[mi][ni] = __builtin_amdgcn_mfma_f32_16x16x32_bf16(
                    afh[mi], bfl[ni], acc[mi][ni], 0, 0, 0);
                acc[mi][ni] = __builtin_amdgcn_mfma_f32_16x16x32_bf16(
                    afh[mi], bfh[ni], acc[mi][ni], 0, 0, 0);
            }
        __syncthreads();
    }

    // D: col = lr, row = lg*4 + j
    #pragma unroll
    for (int ni = 0; ni < 4; ++ni) {
        int col = colBase + wn * 64 + ni * 16 + lr;
        #pragma unroll
        for (int mi = 0; mi < 4; ++mi) {
            int rbase = rowsBase + wm * 64 + mi * 16 + lg * 4;
            #pragma unroll
            for (int j = 0; j < 4; ++j)
                u1[(size_t)(rbase + j) * 256 + col] = acc[mi][ni][j];
        }
    }
}

// ---------------------------------------------------------------------------
// mfma_hi<ACT, AF32>: out = act(A @ BT^T + bias), hi-only bf16 MFMA.
// 256 thr = 4 waves, tile 128x128, K-step 32.
// AF32: A is f32, converted during staging (saves a cvt pass over x).
// ACT 0: gelu -> bf16 out; ACT 1: sigmoid -> f32 out.
// ---------------------------------------------------------------------------
template<int ACT, int AF32>
__global__ __launch_bounds__(256) void mfma_hi(
    const void* __restrict__ Ap, const unsigned short* __restrict__ BT,
    const float* __restrict__ bias, void* __restrict__ outp,
    int N, int K, int colBlocks)
{
    __shared__ unsigned short As[128][40];
    __shared__ unsigned short Bs[128][40];

    const int tid = threadIdx.x;
    const int l = tid & 63;
    const int w = tid >> 6;
    const int wm = w >> 1, wn = w & 1;
    const int lg = l >> 4, lr = l & 15;
    const int rb = blockIdx.x / colBlocks;
    const int cb = blockIdx.x - rb * colBlocks;
    const int rowsBase = rb * 128, colBase = cb * 128;

    f32x4 acc[4][4];
    #pragma unroll
    for (int mi = 0; mi < 4; ++mi)
        #pragma unroll
        for (int ni = 0; ni < 4; ++ni) acc[mi][ni] = (f32x4){0.f, 0.f, 0.f, 0.f};

    for (int kb = 0; kb < K; kb += 32) {
        if (AF32) {
            const float* A = (const float*)Ap;
            #pragma unroll
            for (int m = 0; m < 2; ++m) {
                int flat = m * 256 + tid;
                int row = flat >> 2, seg = flat & 3;
                const float* src = A + (size_t)(rowsBase + row) * K + kb + seg * 8;
                float4 v0 = *(const float4*)src;
                float4 v1 = *(const float4*)(src + 4);
                float f[8] = {v0.x, v0.y, v0.z, v0.w, v1.x, v1.y, v1.z, v1.w};
                short8_t h;
                #pragma unroll
                for (int j = 0; j < 8; ++j) h[j] = (short)f2bf(f[j]);
                *(short8_t*)&As[row][seg * 8] = h;
            }
        } else {
            const unsigned short* A = (const unsigned short*)Ap;
            #pragma unroll
            for (int m = 0; m < 2; ++m) {
                int flat = m * 256 + tid;
                int row = flat >> 2, seg = flat & 3;
                *(short8_t*)&As[row][seg * 8] =
                    *(const short8_t*)(A + (size_t)(rowsBase + row) * K + kb + seg * 8);
            }
        }
        #pragma unroll
        for (int m = 0; m < 2; ++m) {
            int flat = m * 256 + tid;
            int col = flat >> 2, seg = flat & 3;
            *(short8_t*)&Bs[col][seg * 8] =
                *(const short8_t*)(BT + (size_t)(colBase + col) * K + kb + seg * 8);
        }
        __syncthreads();

        short8_t af[4], bf[4];
        #pragma unroll
        for (int mi = 0; mi < 4; ++mi)
            af[mi] = *(const short8_t*)&As[wm * 64 + mi * 16 + lr][lg * 8];
        #pragma unroll
        for (int ni = 0; ni < 4; ++ni)
            bf[ni] = *(const short8_t*)&Bs[wn * 64 + ni * 16 + lr][lg * 8];
        #pragma unroll
        for (int mi = 0; mi < 4; ++mi)
            #pragma unroll
            for (int ni = 0; ni < 4; ++ni)
                acc[mi][ni] = __builtin_amdgcn_mfma_f32_16x16x32_bf16(
                    af[mi], bf[ni], acc[mi][ni], 0, 0, 0);
        __syncthreads();
    }

    #pragma unroll
    for (int ni = 0; ni < 4; ++ni) {
        int col = colBase + wn * 64 + ni * 16 + lr;
        float bv = bias[col];
        #pragma unroll
        for (int mi = 0; mi < 4; ++mi) {
            int rbase = rowsBase + wm * 64 + mi * 16 + lg * 4;
            #pragma unroll
            for (int j = 0; j < 4; ++j) {
                float v = acc[mi][ni][j] + bv;
                if (ACT == 0) {
                    ((unsigned short*)outp)[(size_t)(rbase + j) * N + col] =
                        f2bf(gelu_exact(v));
                } else {
                    ((float*)outp)[(size_t)(rbase + j) * N + col] = sigmoidf_(v);
                }
            }
        }
    }
}

// ---------------------------------------------------------------------------
// k1_epi: h1 = gelu(LN(u1 + b1)); one wave per row
// ---------------------------------------------------------------------------
__global__ __launch_bounds__(256) void k1_epi(
    const float* __restrict__ u1, const float* __restrict__ b1,
    const float* __restrict__ lng, const float* __restrict__ lnb,
    float* __restrict__ h1)
{
    const int wv = threadIdx.x >> 6, l = threadIdx.x & 63;
    const int row = blockIdx.x * 4 + wv;
    float4 a = *(const float4*)(u1 + (size_t)row * 256 + l * 4);
    float4 bb = *(const float4*)(b1 + l * 4);
    float u[4] = {a.x + bb.x, a.y + bb.y, a.z + bb.z, a.w + bb.w};
    float s = u[0] + u[1] + u[2] + u[3];
    float q = u[0]*u[0] + u[1]*u[1] + u[2]*u[2] + u[3]*u[3];
    #pragma unroll
    for (int o = 1; o < 64; o <<= 1) {
        s += __shfl_xor(s, o);
        q += __shfl_xor(q, o);
    }
    float mean = s * (1.0f / 256.0f);
    float var  = q * (1.0f / 256.0f) - mean * mean;
    float rstd = rsqrtf(var + 1e-5f);
    float4 g = *(const float4*)(lng + l * 4);
    float4 be = *(const float4*)(lnb + l * 4);
    float4 o;
    o.x = gelu_exact((u[0] - mean) * rstd * g.x + be.x);
    o.y = gelu_exact((u[1] - mean) * rstd * g.y + be.y);
    o.z = gelu_exact((u[2] - mean) * rstd * g.z + be.z);
    o.w = gelu_exact((u[3] - mean) * rstd * g.w + be.w);
    *(float4*)(h1 + (size_t)row * 256 + l * 4) = o;
}

// ---------------------------------------------------------------------------
// k2a_p: partial u2 = h1[:, kh] @ w2[kh, :]  (fp32, K-split 2)
// ---------------------------------------------------------------------------
__global__ __launch_bounds__(256) void k2a_p(
    const float* __restrict__ h1, const float* __restrict__ w2,
    float* __restrict__ u2p)
{
    __shared__ float xs[32][132];
    __shared__ float ws[32][128];

    const int tid = threadIdx.x;
    const int tc = tid & 15, tr = tid >> 4;
    const int c0 = tc * 4, c1 = 64 + tc * 4, r0 = tr * 8;
    const int rb = blockIdx.x >> 1, half = blockIdx.x & 1;
    const int rowsBase = rb * 128, kBase = half * 128;

    float acc[8][8];
    #pragma unroll
    for (int i = 0; i < 8; ++i)
        #pragma unroll
        for (int j = 0; j < 8; ++j) acc[i][j] = 0.0f;

    for (int kc = 0; kc < 4; ++kc) {
        const int kb = kBase + kc * 32;
        #pragma unroll
        for (int m = 0; m < 4; ++m) {
            int flat = m * 256 + tid;
            int r = flat >> 3, i4 = flat & 7;
            float4 v = *(const float4*)(h1 + (size_t)(rowsBase + r) * 256 + kb + i4 * 4);
            xs[i4*4+0][r] = v.x; xs[i4*4+1][r] = v.y;
            xs[i4*4+2][r] = v.z; xs[i4*4+3][r] = v.w;
        }
        #pragma unroll
        for (int m = 0; m < 4; ++m) {
            int flat = m * 256 + tid;
            int k = flat >> 5, c = (flat & 31) * 4;
            *(float4*)&ws[k][c] = *(const float4*)(w2 + (size_t)(kb + k) * 128 + c);
        }
        __syncthreads();
        #pragma unroll 8
        for (int k = 0; k < 32; ++k) {
            float xv[8], wv8[8];
            *(float4*)&xv[0]  = *(const float4*)&xs[k][r0];
            *(float4*)&xv[4]  = *(const float4*)&xs[k][r0 + 4];
            *(float4*)&wv8[0] = *(const float4*)&ws[k][c0];
            *(float4*)&wv8[4] = *(const float4*)&ws[k][c1];
            #pragma unroll
            for (int i = 0; i < 8; ++i)
                #pragma unroll
                for (int j = 0; j < 8; ++j)
                    acc[i][j] = fmaf(xv[i], wv8[j], acc[i][j]);
        }
        __syncthreads();
    }
    float* dst = u2p + (size_t)half * 4194304;
    #pragma unroll
    for (int i = 0; i < 8; ++i) {
        int row = rowsBase + r0 + i;
        *(float4*)(dst + (size_t)row * 128 + c0) = *(float4*)&acc[i][0];
        *(float4*)(dst + (size_t)row * 128 + c1) = *(float4*)&acc[i][4];
    }
}

// ---------------------------------------------------------------------------
// k3: h2 = gelu(u2p0+u2p1+b2) in-reg; logits = h2@w3 + b3 + gi; probs;
// constrained selection -> sel; scalar partials.
// ---------------------------------------------------------------------------
__global__ __launch_bounds__(128) void k3_router(
    const float* __restrict__ u2p, const float* __restrict__ w3,
    const float* __restrict__ b3, const float* __restrict__ gi,
    const float* __restrict__ b2, float* __restrict__ probsOut,
    float* __restrict__ selOut, float* __restrict__ scal)
{
    __shared__ float ws3[128][8];
    __shared__ float sAct[2], sP[2], sCnt[2][8];

    const int tid = threadIdx.x;
    *(float4*)&ws3[tid][0] = *(const float4*)(w3 + tid * 8);
    *(float4*)&ws3[tid][4] = *(const float4*)(w3 + tid * 8 + 4);
    __syncthreads();

    const int row = blockIdx.x * 128 + tid;
    const float* r0p = u2p + (size_t)row * 128;
    const float* r1p = u2p + 4194304 + (size_t)row * 128;

    float accg[8];
    #pragma unroll
    for (int g = 0; g < 8; ++g) accg[g] = 0.0f;
    #pragma unroll 4
    for (int k4 = 0; k4 < 32; ++k4) {
        float4 a = *(const float4*)(r0p + k4 * 4);
        float4 b = *(const float4*)(r1p + k4 * 4);
        float4 bb = *(const float4*)(b2 + k4 * 4);
        float hv4[4];
        hv4[0] = gelu_exact(a.x + b.x + bb.x);
        hv4[1] = gelu_exact(a.y + b.y + bb.y);
        hv4[2] = gelu_exact(a.z + b.z + bb.z);
        hv4[3] = gelu_exact(a.w + b.w + bb.w);
        #pragma unroll
        for (int t = 0; t < 4; ++t)
            #pragma unroll
            for (int g = 0; g < 8; ++g)
                accg[g] = fmaf(hv4[t], ws3[k4 * 4 + t][g], accg[g]);
    }

    float p[8], gs[8], cnt[8];
    float actCnt = 0.0f, pSum = 0.0f;
    #pragma unroll
    for (int g = 0; g < 8; ++g) {
        float lg = accg[g] + b3[g] + gi[g];
        p[g] = sigmoidf_(lg);
    }
    #pragma unroll
    for (int g = 0; g < 8; ++g) {
        int rank = 0;
        #pragma unroll
        for (int j = 0; j < 8; ++j) {
            rank += (p[j] > p[g]) ? 1 : 0;
            rank += (j < g && p[j] == p[g]) ? 1 : 0;
        }
        float act = (rank < 2) ? 1.0f
                  : ((rank < 6) ? ((p[g] > 0.5f) ? 1.0f : 0.0f) : 0.0f);
        gs[g] = (act - p[g]) + p[g];
        float over = (p[g] > 0.5f) ? 1.0f : 0.0f;
        cnt[g] = over;
        actCnt += over;
        pSum += p[g];
    }

    *(float4*)(probsOut + (size_t)row * 8)     = *(float4*)&p[0];
    *(float4*)(probsOut + (size_t)row * 8 + 4) = *(float4*)&p[4];
    *(float4*)(selOut   + (size_t)row * 8)     = *(float4*)&gs[0];
    *(float4*)(selOut   + (size_t)row * 8 + 4) = *(float4*)&gs[4];

    #pragma unroll
    for (int o = 32; o > 0; o >>= 1) {
        actCnt += __shfl_down(actCnt, o);
        pSum   += __shfl_down(pSum, o);
        #pragma unroll
        for (int g = 0; g < 8; ++g) cnt[g] += __shfl_down(cnt[g], o);
    }
    if ((tid & 63) == 0) {
        int w = tid >> 6;
        sAct[w] = actCnt; sP[w] = pSum;
        #pragma unroll
        for (int g = 0; g < 8; ++g) sCnt[w][g] = cnt[g];
    }
    __syncthreads();
    if (tid == 0) {
        const float invB = 1.0f / 32768.0f;
        atomicAdd(&scal[0], (sAct[0] + sAct[1]) * invB);
        atomicAdd(&scal[9], (sP[0] + sP[1]) * invB);
        #pragma unroll
        for (int g = 0; g < 8; ++g)
            atomicAdd(&scal[1 + g], (sCnt[0][g] + sCnt[1][g]) * invB);
    }
}

// ---------------------------------------------------------------------------
// k4: gmask = repeat(sel); mask = gmask * dwts; active_dims reduce
// ---------------------------------------------------------------------------
__global__ __launch_bounds__(256) void k4_mask(
    const float* __restrict__ sel, const float* __restrict__ dwts,
    float* __restrict__ gmaskOut, float* __restrict__ maskOut,
    float* __restrict__ activeDims)
{
    const int stride = gridDim.x * 256;
    float cntF = 0.0f;
    for (int i4 = blockIdx.x * 256 + threadIdx.x; i4 < 6291456; i4 += stride) {
        int row = i4 / 192;
        int rem = i4 - row * 192;
        int g = rem / 24;
        float v = sel[(size_t)row * 8 + g];
        float4 d = *(const float4*)(dwts + (size_t)i4 * 4);
        float4 gm = {v, v, v, v};
        float4 m = {v * d.x, v * d.y, v * d.z, v * d.w};
        *(float4*)(gmaskOut + (size_t)i4 * 4) = gm;
        *(float4*)(maskOut  + (size_t)i4 * 4) = m;
        cntF += (m.x > 0.5f ? 1.0f : 0.0f) + (m.y > 0.5f ? 1.0f : 0.0f)
              + (m.z > 0.5f ? 1.0f : 0.0f) + (m.w > 0.5f ? 1.0f : 0.0f);
    }
    #pragma unroll
    for (int o = 32; o > 0; o >>= 1) cntF += __shfl_down(cntF, o);
    __shared__ float sc[4];
    if ((threadIdx.x & 63) == 0) sc[threadIdx.x >> 6] = cntF;
    __syncthreads();
    if (threadIdx.x == 0)
        atomicAdd(activeDims, (sc[0] + sc[1] + sc[2] + sc[3]) * (1.0f / 32768.0f));
}

__global__ void kz_zero(float* s) { if (threadIdx.x < 11) s[threadIdx.x] = 0.0f; }

// ---------------------------------------------------------------------------
extern "C" void kernel_launch(void* const* d_in, const int* in_sizes, int n_in,
                              void* d_out, int out_size, void* d_ws, size_t ws_size,
                              hipStream_t stream)
{
    const float* x   = (const float*)d_in[0];
    const float* w1  = (const float*)d_in[1];
    const float* b1  = (const float*)d_in[2];
    const float* lng = (const float*)d_in[3];
    const float* lnb = (const float*)d_in[4];
    const float* w2  = (const float*)d_in[5];
    const float* b2  = (const float*)d_in[6];
    const float* w3  = (const float*)d_in[7];
    const float* b3  = (const float*)d_in[8];
    const float* dw1 = (const float*)d_in[9];
    const float* db1 = (const float*)d_in[10];
    const float* dw2 = (const float*)d_in[11];
    const float* db2 = (const float*)d_in[12];
    const float* gi  = (const float*)d_in[13];

    float* out   = (float*)d_out;
    float* mask  = out;                 // [B,768] output slot
    float* gmask = out + 25165824;      // [B,768] output slot
    float* dwts  = out + 50331648;      // [B,768] output slot
    float* probs = out + 75497472;      // [B,8]
    float* sel   = out + 75759616;      // [B,8]
    float* scal  = out + 76021760;      // 11 scalars

    // scratch in dead output slots:
    // mask slot: u1 [B,256] + h1 [B,256] + u2p [2][B,128]  (dead until k4)
    float* u1  = mask;                       // 8388608 floats
    float* h1  = mask + 8388608;             // 8388608 floats
    float* u2p = mask + 16777216;            // 8388608 floats
    // gmask slot: g1h bf16 [B,256] + converted weights (dead until k4)
    unsigned short* g1h  = (unsigned short*)gmask;                 // 4194304 f32-equiv
    unsigned short* w1Th = (unsigned short*)(gmask + 4194304);     // 98304 f32-equiv
    unsigned short* w1Tl = (unsigned short*)(gmask + 4292608);
    unsigned short* dw1T = (unsigned short*)(gmask + 4390912);
    unsigned short* dw2T = (unsigned short*)(gmask + 4489216);

    kz_zero<<<dim3(1), dim3(64), 0, stream>>>(scal);
    cvt_wall<<<dim3(288), dim3(256), 0, stream>>>(
        w1, dw1, dw2, w1Th, w1Tl, dw1T, dw2T);
    // router path (split-3 MFMA for x@w1; rest fp32)
    mfma_u1<<<dim3(512), dim3(256), 0, stream>>>(x, w1Th, w1Tl, u1);
    k1_epi<<<dim3(8192), dim3(256), 0, stream>>>(u1, b1, lng, lnb, h1);
    k2a_p<<<dim3(512), dim3(256), 0, stream>>>(h1, w2, u2p);
    k3_router<<<dim3(256), dim3(128), 0, stream>>>(
        u2p, w3, b3, gi, b2, probs, sel, scal);
    // dim-importance path (hi-only bf16; boundary 15 sigma away)
    mfma_hi<0, 1><<<dim3(512), dim3(256), 0, stream>>>(
        (const void*)x, dw1T, db1, (void*)g1h, 256, 768, 2);
    mfma_hi<1, 0><<<dim3(1536), dim3(256), 0, stream>>>(
        (const void*)g1h, dw2T, db2, (void*)dwts, 768, 256, 6);
    k4_mask<<<dim3(2048), dim3(256), 0, stream>>>(sel, dwts, gmask, mask, &scal[10]);
}